// Round 15
// baseline (3934.782 us; speedup 1.0000x reference)
//
#include <hip/hip_runtime.h>
#include <hip/hip_bf16.h>

#define BB 512
#define TT 128
#define EE 64
#define HH 512
#define VV 100
#define NG 2048
#define NBLK 256

typedef __attribute__((ext_vector_type(8))) short bf16x8;
typedef __attribute__((ext_vector_type(4))) float f32x4;

__device__ __forceinline__ float sigm(float x) { return 1.f / (1.f + expf(-x)); }
__device__ __forceinline__ float bf2f(unsigned short u) {
  return __uint_as_float(((unsigned)u) << 16);
}
__device__ __forceinline__ unsigned short f2bf(float x) {  // RNE
  unsigned u = __float_as_uint(x);
  return (unsigned short)((u + 0x7fffu + ((u >> 16) & 1u)) >> 16);
}
__device__ __forceinline__ void gl16(void* lds, const void* g) {
  __builtin_amdgcn_global_load_lds((const __attribute__((address_space(1))) void*)g,
                                   (__attribute__((address_space(3))) void*)lds, 16, 0, 0);
}
// agent-scope (L3-coherent, L2-bypass) accesses (slow/cross-XCD path)
__device__ __forceinline__ unsigned long long ald64(const unsigned short* p) {
  return __hip_atomic_load((const unsigned long long*)p, __ATOMIC_RELAXED,
                           __HIP_MEMORY_SCOPE_AGENT);
}
__device__ __forceinline__ unsigned ald32(const unsigned short* p) {
  return __hip_atomic_load((const unsigned*)p, __ATOMIC_RELAXED,
                           __HIP_MEMORY_SCOPE_AGENT);
}
__device__ __forceinline__ void ast32(unsigned short* p, unsigned v) {
  __hip_atomic_store((unsigned*)p, v, __ATOMIC_RELAXED, __HIP_MEMORY_SCOPE_AGENT);
}
__device__ __forceinline__ int ald32i(const int* p) {
  return __hip_atomic_load(p, __ATOMIC_RELAXED, __HIP_MEMORY_SCOPE_AGENT);
}
__device__ __forceinline__ void ast32i(int* p, int v) {
  __hip_atomic_store(p, v, __ATOMIC_RELAXED, __HIP_MEMORY_SCOPE_AGENT);
}

// -------- precompute: P_vocab[v][n] = sum_e emb[v,e] * W0[e, n] --------
__global__ __launch_bounds__(256) void pv_kernel(
    const float* __restrict__ cemb, const float* __restrict__ W0,
    float* __restrict__ Pvocab) {
  int idx = blockIdx.x * 256 + threadIdx.x;
  if (idx >= VV * NG) return;
  int v = idx >> 11, n = idx & (NG - 1);
  float acc = 0.f;
  for (int e = 0; e < EE; e++) acc += cemb[v * EE + e] * W0[e * NG + n];
  Pvocab[idx] = acc;
}

// -------- precompute: P_state = b0 + state @ W0[64:576] --------
__global__ __launch_bounds__(256) void ps_kernel(
    const float* __restrict__ state, const float* __restrict__ W0,
    const float* __restrict__ b0v, float* __restrict__ Pstate) {
  const int rt = blockIdx.x >> 5;
  const int ct = blockIdx.x & 31;
  const int tid = threadIdx.x;
  const int rg = tid >> 4, cg = tid & 15;
  __shared__ float Slds[64][65];
  __shared__ float Wlds[64][65];
  float acc[4][4];
#pragma unroll
  for (int c = 0; c < 4; c++) {
    float bv = b0v[ct * 64 + cg * 4 + c];
#pragma unroll
    for (int r = 0; r < 4; r++) acc[r][c] = bv;
  }
  for (int kc = 0; kc < HH; kc += 64) {
    __syncthreads();
#pragma unroll
    for (int i = 0; i < 16; i++) {
      int e = tid + 256 * i;
      int r = e >> 6, c = e & 63;
      Slds[r][c] = state[(size_t)(rt * 64 + r) * HH + kc + c];
      Wlds[r][c] = W0[(size_t)(EE + kc + r) * NG + ct * 64 + c];
    }
    __syncthreads();
#pragma unroll 1
    for (int kk = 0; kk < 64; kk++) {
      float sv[4], wv[4];
#pragma unroll
      for (int r = 0; r < 4; r++) sv[r] = Slds[rg * 4 + r][kk];
#pragma unroll
      for (int c = 0; c < 4; c++) wv[c] = Wlds[kk][cg * 4 + c];
#pragma unroll
      for (int r = 0; r < 4; r++)
#pragma unroll
        for (int c = 0; c < 4; c++) acc[r][c] += sv[r] * wv[c];
    }
  }
#pragma unroll
  for (int r = 0; r < 4; r++)
#pragma unroll
    for (int c = 0; c < 4; c++)
      Pstate[(size_t)(rt * 64 + rg * 4 + r) * NG + ct * 64 + cg * 4 + c] = acc[r][c];
}

// -------- weight convert: Wf [ct16 32][kc nkch][hl 2][g 4][lane 64][j 8] --------
__global__ __launch_bounds__(256) void wconv_kernel(
    const float* __restrict__ W, int koff, unsigned short* __restrict__ Wf,
    int kcmask, int ctshift) {
  int u = blockIdx.x * 256 + threadIdx.x;
  int j = u & 7;
  int lane = (u >> 3) & 63;
  int g = (u >> 9) & 3;
  int kc = (u >> 11) & kcmask;
  int ct16 = u >> ctshift;
  int q = lane >> 4, c15 = lane & 15;
  int k = kc * 32 + q * 8 + j;
  int col = ct16 * 16 + c15 + g * 512;
  float x = W[(size_t)(koff + k) * NG + col];
  unsigned short hi = f2bf(x);
  unsigned short lo = f2bf(x - bf2f(hi));
  size_t base = ((size_t)(ct16 * (kcmask + 1) + kc)) * 4096 + g * 512 + lane * 8 + j;
  Wf[base] = hi;
  Wf[base + 2048] = lo;
}

// -------- Wp convert: Wpf [kc 16][hl 2][ni 8][lane 64][8] --------
__global__ __launch_bounds__(256) void wconvp_kernel(
    const float* __restrict__ Wp, unsigned short* __restrict__ Wpf) {
  int u = blockIdx.x * 256 + threadIdx.x;
  int j = u & 7;
  int lane = (u >> 3) & 63;
  int ni = (u >> 9) & 7;
  int kc = (u >> 12) & 15;
  int q = lane >> 4, c15 = lane & 15;
  int col = ni * 16 + c15;
  int k = kc * 32 + q * 8 + j;
  float x = (col < VV) ? Wp[(size_t)k * VV + col] : 0.f;
  unsigned short hi = f2bf(x);
  unsigned short lo = f2bf(x - bf2f(hi));
  size_t base = (size_t)kc * 8192 + ni * 512 + lane * 8 + j;
  Wpf[base] = hi;
  Wpf[base + 4096] = lo;
}

// -------- group barrier (vmcnt drained by __syncthreads; data at coherence pt) --------
__device__ __forceinline__ void groupbar(unsigned* ctr, unsigned target) {
  __syncthreads();
  if (threadIdx.x == 0) {
    __hip_atomic_fetch_add(ctr, 1u, __ATOMIC_RELAXED, __HIP_MEMORY_SCOPE_AGENT);
    while (__hip_atomic_load(ctr, __ATOMIC_RELAXED, __HIP_MEMORY_SCOPE_AGENT) < target)
      __builtin_amdgcn_s_sleep(1);
  }
  __builtin_amdgcn_sched_barrier(0);
  __syncthreads();
}

// raw barrier: wait LDS ops only, leave vmem in flight
__device__ __forceinline__ void ldsbar() {
  asm volatile("s_waitcnt lgkmcnt(0)" ::: "memory");
  __builtin_amdgcn_sched_barrier(0);
  __builtin_amdgcn_s_barrier();
  __builtin_amdgcn_sched_barrier(0);
}

// -------- persistent fused kernel --------
// 256 blocks x 512 thr (8 waves = 4 gates x 2 n16). r10 structure with XCD-LOCAL
// row mapping: XCD x owns mb {2x,2x+1} (rows [64x,64x+64)); its 32 blocks cover
// (mb, ct2 0..15). h exchange then stays within one XCD -> volatile (sc0,
// L2-coherent) h path; if dispatch is not exactly 32 blocks/XCD, a uniform flag
// falls back to agent atomics (r10 behavior).
__global__ __launch_bounds__(512, 1) void fused_kernel(
    const int* __restrict__ tok, const int* __restrict__ lens,
    const float* __restrict__ Pstate, const float* __restrict__ Pvocab,
    const unsigned short* __restrict__ W0f, const unsigned short* __restrict__ W1f,
    const float* __restrict__ b1,
    unsigned short* __restrict__ h0f, unsigned short* __restrict__ h1f,
    float* __restrict__ c0, float* __restrict__ c1,
    unsigned short* __restrict__ outsF, unsigned int* __restrict__ bar,
    int* __restrict__ slots) {
  const int bid = blockIdx.x;
  const int tid = threadIdx.x;
  const int wg = (tid >> 6) & 3;  // gate
  const int wn = tid >> 8;        // n16 half
  const int lane = tid & 63, c15 = lane & 15, q = lane >> 4;

  __shared__ __align__(16) unsigned short ldsA[2][2048];  // [buf][hl][mf][lane][8]
  __shared__ float xch[2][32][132];
  __shared__ int s_slots[NBLK];
  __shared__ int s_tile;
  __shared__ int s_fast;

  // ---- publish measured XCD, rank -> tile ----
  if (tid == 0) {
    unsigned xcd;
    asm volatile("s_getreg_b32 %0, hwreg(HW_REG_XCC_ID, 0, 32)" : "=s"(xcd));
    ast32i(&slots[bid], (int)(xcd & 7));
  }
  groupbar(bar, NBLK);
  if (tid < NBLK) s_slots[tid] = ald32i(&slots[tid]) & 7;
  __syncthreads();
  if (tid == 0) {
    int myx = s_slots[bid];
    int n[8] = {0, 0, 0, 0, 0, 0, 0, 0};
    int rank = 0;
    for (int i = 0; i < NBLK; i++) {
      int v = s_slots[i];
      if (v == myx && i < bid) rank++;
      n[v]++;
    }
    int tile;
    if (rank < 32) {
      tile = myx * 32 + rank;
    } else {
      int o = rank - 32;
      for (int x2 = 0; x2 < myx; x2++) o += (n[x2] > 32) ? (n[x2] - 32) : 0;
      tile = 0;
      for (int x2 = 0; x2 < 8; x2++) {
        int d = 32 - n[x2];
        if (d > 0) {
          if (o < d) { tile = x2 * 32 + n[x2] + o; break; }
          o -= d;
        }
      }
    }
    s_tile = tile;
    int ok = 1;
    for (int x2 = 0; x2 < 8; x2++) ok &= (n[x2] == 32);
    s_fast = ok;
  }
  __syncthreads();
  const int tile = s_tile;
  const bool fastp = (s_fast != 0);
  // XCD-local decode: XCD = tile>>5 owns mb {2*XCD, 2*XCD+1}
  const int mb = 2 * (tile >> 5) + ((tile >> 4) & 1);  // 0..15 (32-row group)
  const int ct2 = tile & 15;                           // 0..15 (32-cell tile)

  const size_t hchunk = (size_t)(mb >> 1) * 16;
  const int mfbase = (mb & 1) * 2;
  unsigned* gctr = bar + 64 + mb * 64;  // per-group counter (own line)

  // A staging decode: 512 u64 words cover one 2048-short chunk
  const int w_hl = tid >> 8;
  const int w_mf = (tid >> 7) & 1;
  const int w_r = tid & 127;
  const size_t a_src = (size_t)w_hl * 2048 + (size_t)(mfbase + w_mf) * 512 + w_r * 4;
  const int a_lds = w_hl * 1024 + w_mf * 512 + w_r * 4;

  // B per-wave source bases (fragment layout: [hl2][g4][lane][8] within 4096-chunk)
  const unsigned short* w0base = W0f + ((size_t)(2 * ct2 + wn) * 16) * 4096 + wg * 512 + lane * 8;
  const unsigned short* w1base = W1f + ((size_t)(2 * ct2 + wn) * 32) * 4096 + wg * 512 + lane * 8;

  for (int p = 0; p <= TT; p++) {
    const int wrb = p & 1, rdb = wrb ^ 1;
    const unsigned short* h0r = h0f + (size_t)rdb * 524288;
    const unsigned short* h1r = h1f + (size_t)rdb * 524288;
    unsigned short* h0w = h0f + (size_t)wrb * 524288;
    unsigned short* h1w = h1f + (size_t)wrb * 524288;
    const bool do0 = (p < TT), do1 = (p >= 1);
    const int t0 = p, t1 = p - 1;

    f32x4 acc0[2], acc1[2];  // [mfrag] for this wave's (gate wg, n16 wn)
    if (do0) {
#pragma unroll
      for (int mf = 0; mf < 2; mf++)
#pragma unroll
        for (int i = 0; i < 4; i++) {
          int row = mb * 32 + mf * 16 + q * 4 + i;
          int tk = tok[row * TT + t0];
          int col = ct2 * 32 + wn * 16 + c15 + wg * 512;
          acc0[mf][i] = Pstate[(size_t)row * NG + col] + Pvocab[(size_t)tk * NG + col];
        }
    }
    if (do1) {
      float bv = b1[ct2 * 32 + wn * 16 + c15 + wg * 512];
#pragma unroll
      for (int mf = 0; mf < 2; mf++)
#pragma unroll
        for (int i = 0; i < 4; i++) acc1[mf][i] = bv;
    }

    auto aload = [&](int kc) -> unsigned long long {
      const unsigned short* hb = (kc < 16) ? h0r : h1r;
      const unsigned short* pp = hb + (hchunk + (kc & 15)) * 4096 + a_src;
      if (fastp) return *(volatile const unsigned long long*)pp;
      return ald64(pp);
    };
    auto dswr = [&](int sb, unsigned long long v) {
      *(unsigned long long*)&ldsA[sb][a_lds] = v;
    };
    auto mmac = [&](int sb, bool on0, bf16x8 B0h, bf16x8 B0l, bf16x8 B1h, bf16x8 B1l) {
      bf16x8 ahi0 = *(const bf16x8*)&ldsA[sb][lane * 8];
      bf16x8 ahi1 = *(const bf16x8*)&ldsA[sb][512 + lane * 8];
      bf16x8 alo0 = *(const bf16x8*)&ldsA[sb][1024 + lane * 8];
      bf16x8 alo1 = *(const bf16x8*)&ldsA[sb][1536 + lane * 8];
      if (on0) {
        acc0[0] = __builtin_amdgcn_mfma_f32_16x16x32_bf16(ahi0, B0h, acc0[0], 0, 0, 0);
        acc0[0] = __builtin_amdgcn_mfma_f32_16x16x32_bf16(ahi0, B0l, acc0[0], 0, 0, 0);
        acc0[0] = __builtin_amdgcn_mfma_f32_16x16x32_bf16(alo0, B0h, acc0[0], 0, 0, 0);
        acc0[1] = __builtin_amdgcn_mfma_f32_16x16x32_bf16(ahi1, B0h, acc0[1], 0, 0, 0);
        acc0[1] = __builtin_amdgcn_mfma_f32_16x16x32_bf16(ahi1, B0l, acc0[1], 0, 0, 0);
        acc0[1] = __builtin_amdgcn_mfma_f32_16x16x32_bf16(alo1, B0h, acc0[1], 0, 0, 0);
      }
      if (do1) {
        acc1[0] = __builtin_amdgcn_mfma_f32_16x16x32_bf16(ahi0, B1h, acc1[0], 0, 0, 0);
        acc1[0] = __builtin_amdgcn_mfma_f32_16x16x32_bf16(ahi0, B1l, acc1[0], 0, 0, 0);
        acc1[0] = __builtin_amdgcn_mfma_f32_16x16x32_bf16(alo0, B1h, acc1[0], 0, 0, 0);
        acc1[1] = __builtin_amdgcn_mfma_f32_16x16x32_bf16(ahi1, B1h, acc1[1], 0, 0, 0);
        acc1[1] = __builtin_amdgcn_mfma_f32_16x16x32_bf16(ahi1, B1l, acc1[1], 0, 0, 0);
        acc1[1] = __builtin_amdgcn_mfma_f32_16x16x32_bf16(alo1, B1h, acc1[1], 0, 0, 0);
      }
    };

    const int R = do1 ? 32 : 16;

    // B register pipeline: Ba=B(kc), Bb=B(kc+1); Bc/Bd = incoming kc+2/kc+3
    bf16x8 Ba0h = {}, Ba0l = {}, Ba1h = {}, Ba1l = {};
    bf16x8 Bb0h = {}, Bb0l = {}, Bb1h = {}, Bb1l = {};
    bf16x8 Bc0h = {}, Bc0l = {}, Bc1h = {}, Bc1l = {};
    bf16x8 Bd0h = {}, Bd0l = {}, Bd1h = {}, Bd1l = {};
    if (do0) {
      Ba0h = *(const bf16x8*)(w0base);
      Ba0l = *(const bf16x8*)(w0base + 2048);
      Bb0h = *(const bf16x8*)(w0base + 4096);
      Bb0l = *(const bf16x8*)(w0base + 4096 + 2048);
    }
    if (do1) {
      Ba1h = *(const bf16x8*)(w1base);
      Ba1l = *(const bf16x8*)(w1base + 2048);
      Bb1h = *(const bf16x8*)(w1base + 4096);
      Bb1l = *(const bf16x8*)(w1base + 4096 + 2048);
    }
    unsigned long long a0v = aload(0);
    unsigned long long aN1 = aload(1);
    unsigned long long aN2 = aload(2);
    dswr(0, a0v);
    ldsbar();

#pragma unroll 1
    for (int kc = 0; kc < R; kc += 2) {
      unsigned long long aF0 = aload(kc + 3);
      unsigned long long aF1 = aload(kc + 4);
      if (do0 && kc + 2 < 16) {
        const unsigned short* s = w0base + (size_t)(kc + 2) * 4096;
        Bc0h = *(const bf16x8*)(s);
        Bc0l = *(const bf16x8*)(s + 2048);
      }
      if (do1 && kc + 2 < R) {
        const unsigned short* s = w1base + (size_t)(kc + 2) * 4096;
        Bc1h = *(const bf16x8*)(s);
        Bc1l = *(const bf16x8*)(s + 2048);
      }
      if (do0 && kc + 3 < 16) {
        const unsigned short* s = w0base + (size_t)(kc + 3) * 4096;
        Bd0h = *(const bf16x8*)(s);
        Bd0l = *(const bf16x8*)(s + 2048);
      }
      if (do1 && kc + 3 < R) {
        const unsigned short* s = w1base + (size_t)(kc + 3) * 4096;
        Bd1h = *(const bf16x8*)(s);
        Bd1l = *(const bf16x8*)(s + 2048);
      }
      dswr(1, aN1);
      mmac(0, do0 && kc < 16, Ba0h, Ba0l, Ba1h, Ba1l);
      ldsbar();
      dswr(0, aN2);
      mmac(1, do0 && kc + 1 < 16, Bb0h, Bb0l, Bb1h, Bb1l);
      ldsbar();
      aN1 = aF0; aN2 = aF1;
      Ba0h = Bc0h; Ba0l = Bc0l; Ba1h = Bc1h; Ba1l = Bc1l;
      Bb0h = Bd0h; Bb0l = Bd0l; Bb1h = Bd1h; Bb1l = Bd1l;
    }

    // ---- merged epilogue ----
    if (do0) {
#pragma unroll
      for (int mf = 0; mf < 2; mf++)
#pragma unroll
        for (int i = 0; i < 4; i++)
          xch[0][mf * 16 + q * 4 + i][wg * 32 + wn * 16 + c15] = acc0[mf][i];
    }
    if (do1) {
#pragma unroll
      for (int mf = 0; mf < 2; mf++)
#pragma unroll
        for (int i = 0; i < 4; i++)
          xch[1][mf * 16 + q * 4 + i][wg * 32 + wn * 16 + c15] = acc1[mf][i];
    }
    __syncthreads();
    {
      int rr = tid >> 4, cc = (tid & 15) * 2;
      int row = mb * 32 + rr;
      int cell = ct2 * 32 + cc;
      int qp = cc >> 3, jp = cc & 7;
      size_t hb = (hchunk + ct2) * 4096 + (size_t)(mfbase + (rr >> 4)) * 512 +
                  (size_t)((rr & 15) | (qp << 4)) * 8 + jp;
      int len = lens[row];
      if (do0) {
        bool msk = t0 < len;
        unsigned hhp, hlp;
        if (msk) {
          float gi0 = xch[0][rr][cc], gj0 = xch[0][rr][32 + cc];
          float gf0 = xch[0][rr][64 + cc], go0 = xch[0][rr][96 + cc];
          float gi1 = xch[0][rr][cc + 1], gj1 = xch[0][rr][33 + cc];
          float gf1 = xch[0][rr][65 + cc], go1 = xch[0][rr][97 + cc];
          size_t sidx = (size_t)row * HH + cell;
          float nca = c0[sidx] * sigm(gf0 + 1.f) + sigm(gi0) * tanhf(gj0);
          float ncb = c0[sidx + 1] * sigm(gf1 + 1.f) + sigm(gi1) * tanhf(gj1);
          float nha = tanhf(nca) * sigm(go0);
          float nhb = tanhf(ncb) * sigm(go1);
          c0[sidx] = nca; c0[sidx + 1] = ncb;
          unsigned short ha = f2bf(nha), hbq = f2bf(nhb);
          unsigned short la = f2bf(nha - bf2f(ha)), lb = f2bf(nhb - bf2f(hbq));
          hhp = ha | ((unsigned)hbq << 16);
          hlp = la | ((unsigned)lb << 16);
        } else {
          if (fastp) {
            hhp = *(volatile const unsigned*)(h0r + hb);
            hlp = *(volatile const unsigned*)(h0r + hb + 2048);
          } else {
            hhp = ald32(h0r + hb);
            hlp = ald32(h0r + hb + 2048);
          }
        }
        if (fastp) {
          *(volatile unsigned*)(h0w + hb) = hhp;
          *(volatile unsigned*)(h0w + hb + 2048) = hlp;
        } else {
          ast32(h0w + hb, hhp);
          ast32(h0w + hb + 2048, hlp);
        }
      }
      if (do1) {
        bool msk = t1 < len;
        unsigned hhp, hlp;
        if (msk) {
          float gi0 = xch[1][rr][cc], gj0 = xch[1][rr][32 + cc];
          float gf0 = xch[1][rr][64 + cc], go0 = xch[1][rr][96 + cc];
          float gi1 = xch[1][rr][cc + 1], gj1 = xch[1][rr][33 + cc];
          float gf1 = xch[1][rr][65 + cc], go1 = xch[1][rr][97 + cc];
          size_t sidx = (size_t)row * HH + cell;
          float nca = c1[sidx] * sigm(gf0 + 1.f) + sigm(gi0) * tanhf(gj0);
          float ncb = c1[sidx + 1] * sigm(gf1 + 1.f) + sigm(gi1) * tanhf(gj1);
          float nha = tanhf(nca) * sigm(go0);
          float nhb = tanhf(ncb) * sigm(go1);
          c1[sidx] = nca; c1[sidx + 1] = ncb;
          unsigned short ha = f2bf(nha), hbq = f2bf(nhb);
          unsigned short la = f2bf(nha - bf2f(ha)), lb = f2bf(nhb - bf2f(hbq));
          hhp = ha | ((unsigned)hbq << 16);
          hlp = la | ((unsigned)lb << 16);
        } else {
          if (fastp) {
            hhp = *(volatile const unsigned*)(h1r + hb);
            hlp = *(volatile const unsigned*)(h1r + hb + 2048);
          } else {
            hhp = ald32(h1r + hb);
            hlp = ald32(h1r + hb + 2048);
          }
        }
        if (fastp) {
          *(volatile unsigned*)(h1w + hb) = hhp;
          *(volatile unsigned*)(h1w + hb + 2048) = hlp;
        } else {
          ast32(h1w + hb, hhp);
          ast32(h1w + hb + 2048, hlp);
        }
        unsigned op = msk ? hhp : 0u;
        size_t oidx = ((size_t)row * 2 + (t1 >> 6)) * 32768 + (size_t)ct2 * 2048 +
                      (size_t)((t1 >> 4) & 3) * 512 +
                      (size_t)((t1 & 15) | (qp << 4)) * 8 + jp;
        *(unsigned*)&outsF[oidx] = op;
      }
    }

    if (p == TT) break;
    // per-mb group barrier: only the 16 blocks sharing these rows
    groupbar(gctr, 16u * (unsigned)(p + 1));
  }
}

// -------- projection via MFMA --------
__global__ __launch_bounds__(128) void proj_kernel(
    const unsigned short* __restrict__ outsF, const unsigned short* __restrict__ Wpf,
    const float* __restrict__ bp, float* __restrict__ out) {
  const int btile = blockIdx.x;
  const int tid = threadIdx.x;
  const int wN = tid >> 6;
  const int lane = tid & 63;
  const int c15 = lane & 15, q = lane >> 4;

  __shared__ __align__(16) unsigned short ldsA[2 * 2048];
  __shared__ __align__(16) unsigned short ldsB2[2 * 8192];

  f32x4 acc[4][4];
#pragma unroll
  for (int m = 0; m < 4; m++)
#pragma unroll
    for (int g = 0; g < 4; g++)
#pragma unroll
      for (int i = 0; i < 4; i++) acc[m][g][i] = 0.f;

  const unsigned short* asrcb = outsF + (size_t)btile * 32768;

  auto stageK = [&](int kc, int buf) {
#pragma unroll
    for (int i2 = 0; i2 < 8; i2++) {
      int f = wN * 8 + i2;
      gl16(&ldsB2[buf * 8192 + f * 512 + lane * 8],
           Wpf + (size_t)kc * 8192 + f * 512 + lane * 8);
    }
#pragma unroll
    for (int i2 = 0; i2 < 2; i2++) {
      int f = wN * 2 + i2;
      gl16(&ldsA[buf * 2048 + f * 512 + lane * 8],
           asrcb + (size_t)kc * 2048 + f * 512 + lane * 8);
    }
  };

  stageK(0, 0);
  __syncthreads();
  for (int kc = 0; kc < 16; kc++) {
    const int buf = kc & 1;
    if (kc + 1 < 16) stageK(kc + 1, buf ^ 1);
    bf16x8 a[4];
#pragma unroll
    for (int m = 0; m < 4; m++)
      a[m] = *(const bf16x8*)&ldsA[buf * 2048 + m * 512 + lane * 8];
#pragma unroll
    for (int g = 0; g < 4; g++) {
      int ni = wN * 4 + g;
      bf16x8 bhi = *(const bf16x8*)&ldsB2[buf * 8192 + ni * 512 + lane * 8];
      bf16x8 blo = *(const bf16x8*)&ldsB2[buf * 8192 + 4096 + ni * 512 + lane * 8];
#pragma unroll
      for (int m = 0; m < 4; m++) {
        acc[m][g] = __builtin_amdgcn_mfma_f32_16x16x32_bf16(a[m], bhi, acc[m][g], 0, 0, 0);
        acc[m][g] = __builtin_amdgcn_mfma_f32_16x16x32_bf16(a[m], blo, acc[m][g], 0, 0, 0);
      }
    }
    __syncthreads();
  }

#pragma unroll
  for (int g = 0; g < 4; g++) {
    int col = (wN * 4 + g) * 16 + c15;
    if (col < VV) {
      float bpv = bp[col];
#pragma unroll
      for (int m = 0; m < 4; m++)
#pragma unroll
        for (int i = 0; i < 4; i++) {
          int rowBT = btile * 64 + m * 16 + q * 4 + i;
          out[(size_t)rowBT * VV + col] = acc[m][g][i] + bpv;
        }
    }
  }
}

extern "C" void kernel_launch(void* const* d_in, const int* in_sizes, int n_in,
                              void* d_out, int out_size, void* d_ws, size_t ws_size,
                              hipStream_t stream) {
  const int* tok = (const int*)d_in[0];
  const int* lens = (const int*)d_in[1];
  const float* state = (const float*)d_in[2];
  const float* cemb = (const float*)d_in[3];
  const float* W0 = (const float*)d_in[4];
  const float* b0 = (const float*)d_in[5];
  const float* W1 = (const float*)d_in[6];
  const float* b1 = (const float*)d_in[7];
  const float* Wp = (const float*)d_in[8];
  const float* bp = (const float*)d_in[9];
  float* out = (float*)d_out;

  char* wsp = (char*)d_ws;
  float* Pstate = (float*)wsp; wsp += (size_t)BB * NG * 4;                        // 4 MB
  float* Pvocab = (float*)wsp; wsp += (size_t)VV * NG * 4;                        // 800 KB
  unsigned short* W0f = (unsigned short*)wsp; wsp += (size_t)32 * 16 * 4096 * 2;  // 4 MB
  unsigned short* W1f = (unsigned short*)wsp; wsp += (size_t)32 * 32 * 4096 * 2;  // 8 MB
  unsigned short* Wpf = (unsigned short*)wsp; wsp += (size_t)16 * 8192 * 2;       // 256 KB
  unsigned short* h0f = (unsigned short*)wsp; wsp += (size_t)2 * 524288 * 2;      // 2 MB
  unsigned short* h1f = (unsigned short*)wsp; wsp += (size_t)2 * 524288 * 2;      // 2 MB
  float* c0 = (float*)wsp; wsp += (size_t)BB * HH * 4;                            // 1 MB
  float* c1 = (float*)wsp; wsp += (size_t)BB * HH * 4;                            // 1 MB
  unsigned int* bar = (unsigned int*)wsp; wsp += 8192;  // [0]=init, 64+64*mb=group
  int* slots = (int*)wsp; wsp += 1024;
  unsigned short* outsF = (unsigned short*)wsp;                                   // 64 MB

  // zero h0f,h1f,c0,c1,bar,slots (contiguous)
  hipMemsetAsync(h0f, 0, (size_t)6 * 1048576 + 8192 + 1024, stream);

  pv_kernel<<<(VV * NG + 255) / 256, 256, 0, stream>>>(cemb, W0, Pvocab);
  ps_kernel<<<256, 256, 0, stream>>>(state, W0, b0, Pstate);
  wconv_kernel<<<4096, 256, 0, stream>>>(W0, EE + HH, W0f, 15, 15);
  wconv_kernel<<<8192, 256, 0, stream>>>(W1, 0, W1f, 31, 16);
  wconvp_kernel<<<(16 * 4096) / 256, 256, 0, stream>>>(Wp, Wpf);

  fused_kernel<<<NBLK, 512, 0, stream>>>(tok, lens, Pstate, Pvocab, W0f, W1f, b1,
                                         h0f, h1f, c0, c1, outsF, bar, slots);

  proj_kernel<<<BB * TT / 64, 128, 0, stream>>>(outsF, Wpf, bp, out);
}

// Round 16
// 2753.769 us; speedup vs baseline: 1.4289x; 1.4289x over previous
//
#include <hip/hip_runtime.h>
#include <hip/hip_bf16.h>

#define BB 512
#define TT 128
#define EE 64
#define HH 512
#define VV 100
#define NG 2048
#define NBLK 256

typedef __attribute__((ext_vector_type(8))) short bf16x8;
typedef __attribute__((ext_vector_type(4))) float f32x4;

__device__ __forceinline__ float sigm(float x) { return 1.f / (1.f + expf(-x)); }
__device__ __forceinline__ float bf2f(unsigned short u) {
  return __uint_as_float(((unsigned)u) << 16);
}
__device__ __forceinline__ unsigned short f2bf(float x) {  // RNE
  unsigned u = __float_as_uint(x);
  return (unsigned short)((u + 0x7fffu + ((u >> 16) & 1u)) >> 16);
}
__device__ __forceinline__ void gl16(void* lds, const void* g) {
  __builtin_amdgcn_global_load_lds((const __attribute__((address_space(1))) void*)g,
                                   (__attribute__((address_space(3))) void*)lds, 16, 0, 0);
}
// agent-scope (L3-coherent, L2-bypass) accesses for cross-block data (h)
__device__ __forceinline__ unsigned long long ald64(const unsigned short* p) {
  return __hip_atomic_load((const unsigned long long*)p, __ATOMIC_RELAXED,
                           __HIP_MEMORY_SCOPE_AGENT);
}
__device__ __forceinline__ unsigned ald32(const unsigned short* p) {
  return __hip_atomic_load((const unsigned*)p, __ATOMIC_RELAXED,
                           __HIP_MEMORY_SCOPE_AGENT);
}
__device__ __forceinline__ void ast32(unsigned short* p, unsigned v) {
  __hip_atomic_store((unsigned*)p, v, __ATOMIC_RELAXED, __HIP_MEMORY_SCOPE_AGENT);
}
__device__ __forceinline__ int ald32i(const int* p) {
  return __hip_atomic_load(p, __ATOMIC_RELAXED, __HIP_MEMORY_SCOPE_AGENT);
}
__device__ __forceinline__ void ast32i(int* p, int v) {
  __hip_atomic_store(p, v, __ATOMIC_RELAXED, __HIP_MEMORY_SCOPE_AGENT);
}

// -------- precompute: P_vocab[v][n] = sum_e emb[v,e] * W0[e, n] --------
__global__ __launch_bounds__(256) void pv_kernel(
    const float* __restrict__ cemb, const float* __restrict__ W0,
    float* __restrict__ Pvocab) {
  int idx = blockIdx.x * 256 + threadIdx.x;
  if (idx >= VV * NG) return;
  int v = idx >> 11, n = idx & (NG - 1);
  float acc = 0.f;
  for (int e = 0; e < EE; e++) acc += cemb[v * EE + e] * W0[e * NG + n];
  Pvocab[idx] = acc;
}

// -------- precompute: P_state = b0 + state @ W0[64:576] --------
__global__ __launch_bounds__(256) void ps_kernel(
    const float* __restrict__ state, const float* __restrict__ W0,
    const float* __restrict__ b0v, float* __restrict__ Pstate) {
  const int rt = blockIdx.x >> 5;
  const int ct = blockIdx.x & 31;
  const int tid = threadIdx.x;
  const int rg = tid >> 4, cg = tid & 15;
  __shared__ float Slds[64][65];
  __shared__ float Wlds[64][65];
  float acc[4][4];
#pragma unroll
  for (int c = 0; c < 4; c++) {
    float bv = b0v[ct * 64 + cg * 4 + c];
#pragma unroll
    for (int r = 0; r < 4; r++) acc[r][c] = bv;
  }
  for (int kc = 0; kc < HH; kc += 64) {
    __syncthreads();
#pragma unroll
    for (int i = 0; i < 16; i++) {
      int e = tid + 256 * i;
      int r = e >> 6, c = e & 63;
      Slds[r][c] = state[(size_t)(rt * 64 + r) * HH + kc + c];
      Wlds[r][c] = W0[(size_t)(EE + kc + r) * NG + ct * 64 + c];
    }
    __syncthreads();
#pragma unroll 1
    for (int kk = 0; kk < 64; kk++) {
      float sv[4], wv[4];
#pragma unroll
      for (int r = 0; r < 4; r++) sv[r] = Slds[rg * 4 + r][kk];
#pragma unroll
      for (int c = 0; c < 4; c++) wv[c] = Wlds[kk][cg * 4 + c];
#pragma unroll
      for (int r = 0; r < 4; r++)
#pragma unroll
        for (int c = 0; c < 4; c++) acc[r][c] += sv[r] * wv[c];
    }
  }
#pragma unroll
  for (int r = 0; r < 4; r++)
#pragma unroll
    for (int c = 0; c < 4; c++)
      Pstate[(size_t)(rt * 64 + rg * 4 + r) * NG + ct * 64 + cg * 4 + c] = acc[r][c];
}

// -------- weight convert: Wf [ct16 32][kc nkch][hl 2][g 4][lane 64][j 8] --------
__global__ __launch_bounds__(256) void wconv_kernel(
    const float* __restrict__ W, int koff, unsigned short* __restrict__ Wf,
    int kcmask, int ctshift) {
  int u = blockIdx.x * 256 + threadIdx.x;
  int j = u & 7;
  int lane = (u >> 3) & 63;
  int g = (u >> 9) & 3;
  int kc = (u >> 11) & kcmask;
  int ct16 = u >> ctshift;
  int q = lane >> 4, c15 = lane & 15;
  int k = kc * 32 + q * 8 + j;
  int col = ct16 * 16 + c15 + g * 512;
  float x = W[(size_t)(koff + k) * NG + col];
  unsigned short hi = f2bf(x);
  unsigned short lo = f2bf(x - bf2f(hi));
  size_t base = ((size_t)(ct16 * (kcmask + 1) + kc)) * 4096 + g * 512 + lane * 8 + j;
  Wf[base] = hi;
  Wf[base + 2048] = lo;
}

// -------- Wp convert: Wpf [kc 16][hl 2][ni 8][lane 64][8] --------
__global__ __launch_bounds__(256) void wconvp_kernel(
    const float* __restrict__ Wp, unsigned short* __restrict__ Wpf) {
  int u = blockIdx.x * 256 + threadIdx.x;
  int j = u & 7;
  int lane = (u >> 3) & 63;
  int ni = (u >> 9) & 7;
  int kc = (u >> 12) & 15;
  int q = lane >> 4, c15 = lane & 15;
  int col = ni * 16 + c15;
  int k = kc * 32 + q * 8 + j;
  float x = (col < VV) ? Wp[(size_t)k * VV + col] : 0.f;
  unsigned short hi = f2bf(x);
  unsigned short lo = f2bf(x - bf2f(hi));
  size_t base = (size_t)kc * 8192 + ni * 512 + lane * 8 + j;
  Wpf[base] = hi;
  Wpf[base + 4096] = lo;
}

// -------- group barrier: no fence (sc1 data ops complete at L3 via vmcnt drain) --------
__device__ __forceinline__ void groupbar(unsigned* ctr, unsigned target) {
  __syncthreads();  // each wave drains its vmcnt -> all sc1 stores at L3
  if (threadIdx.x == 0) {
    __hip_atomic_fetch_add(ctr, 1u, __ATOMIC_RELAXED, __HIP_MEMORY_SCOPE_AGENT);
    while (__hip_atomic_load(ctr, __ATOMIC_RELAXED, __HIP_MEMORY_SCOPE_AGENT) < target)
      __builtin_amdgcn_s_sleep(1);
  }
  __builtin_amdgcn_sched_barrier(0);
  __syncthreads();
}

// raw barrier: wait LDS ops only, leave vmem in flight
__device__ __forceinline__ void ldsbar() {
  asm volatile("s_waitcnt lgkmcnt(0)" ::: "memory");
  __builtin_amdgcn_sched_barrier(0);
  __builtin_amdgcn_s_barrier();
  __builtin_amdgcn_sched_barrier(0);
}

// -------- persistent fused kernel (r10 best-known configuration) --------
// 256 blocks x 512 thr (8 waves = 4 gates x 2 n16). Tile via measured-XCD rank.
// Per-mb GROUP barriers (16 blocks each) - groups are independent pipelines.
// B: per-wave global->VGPR, 2-3 chunk prefetch. A (h): sc1 atomics -> LDS, 5-6 deep.
__global__ __launch_bounds__(512, 1) void fused_kernel(
    const int* __restrict__ tok, const int* __restrict__ lens,
    const float* __restrict__ Pstate, const float* __restrict__ Pvocab,
    const unsigned short* __restrict__ W0f, const unsigned short* __restrict__ W1f,
    const float* __restrict__ b1,
    unsigned short* __restrict__ h0f, unsigned short* __restrict__ h1f,
    float* __restrict__ c0, float* __restrict__ c1,
    unsigned short* __restrict__ outsF, unsigned int* __restrict__ bar,
    int* __restrict__ slots) {
  const int bid = blockIdx.x;
  const int tid = threadIdx.x;
  const int wg = (tid >> 6) & 3;  // gate
  const int wn = tid >> 8;        // n16 half
  const int lane = tid & 63, c15 = lane & 15, q = lane >> 4;

  __shared__ __align__(16) unsigned short ldsA[2][2048];  // [buf][hl][mf][lane][8]
  __shared__ float xch[2][32][132];
  __shared__ int s_slots[NBLK];
  __shared__ int s_tile;

  // ---- publish measured XCD, rank -> tile ----
  if (tid == 0) {
    unsigned xcd;
    asm volatile("s_getreg_b32 %0, hwreg(HW_REG_XCC_ID, 0, 32)" : "=s"(xcd));
    ast32i(&slots[bid], (int)(xcd & 7));
  }
  groupbar(bar, NBLK);
  if (tid < NBLK) s_slots[tid] = ald32i(&slots[tid]) & 7;
  __syncthreads();
  if (tid == 0) {
    int myx = s_slots[bid];
    int n[8] = {0, 0, 0, 0, 0, 0, 0, 0};
    int rank = 0;
    for (int i = 0; i < NBLK; i++) {
      int v = s_slots[i];
      if (v == myx && i < bid) rank++;
      n[v]++;
    }
    int tile;
    if (rank < 32) {
      tile = myx * 32 + rank;
    } else {
      int o = rank - 32;
      for (int x2 = 0; x2 < myx; x2++) o += (n[x2] > 32) ? (n[x2] - 32) : 0;
      tile = 0;
      for (int x2 = 0; x2 < 8; x2++) {
        int d = 32 - n[x2];
        if (d > 0) {
          if (o < d) { tile = x2 * 32 + n[x2] + o; break; }
          o -= d;
        }
      }
    }
    s_tile = tile;
  }
  __syncthreads();
  const int tile = s_tile;
  const int ct2 = 2 * (tile >> 5) + (tile & 1);  // XCD-affine column tile
  const int mb = (tile & 31) >> 1;               // 32-row slice = GROUP id

  const size_t hchunk = (size_t)(mb >> 1) * 16;
  const int mfbase = (mb & 1) * 2;
  unsigned* gctr = bar + 64 + mb * 64;  // per-group counter (own line)

  // A staging decode: 512 u64 words cover one 2048-short chunk
  const int w_hl = tid >> 8;
  const int w_mf = (tid >> 7) & 1;
  const int w_r = tid & 127;
  const size_t a_src = (size_t)w_hl * 2048 + (size_t)(mfbase + w_mf) * 512 + w_r * 4;
  const int a_lds = w_hl * 1024 + w_mf * 512 + w_r * 4;

  // B per-wave source bases (fragment layout: [hl2][g4][lane][8] within 4096-chunk)
  const unsigned short* w0base = W0f + ((size_t)(2 * ct2 + wn) * 16) * 4096 + wg * 512 + lane * 8;
  const unsigned short* w1base = W1f + ((size_t)(2 * ct2 + wn) * 32) * 4096 + wg * 512 + lane * 8;

  for (int p = 0; p <= TT; p++) {
    const int wrb = p & 1, rdb = wrb ^ 1;
    const unsigned short* h0r = h0f + (size_t)rdb * 524288;
    const unsigned short* h1r = h1f + (size_t)rdb * 524288;
    unsigned short* h0w = h0f + (size_t)wrb * 524288;
    unsigned short* h1w = h1f + (size_t)wrb * 524288;
    const bool do0 = (p < TT), do1 = (p >= 1);
    const int t0 = p, t1 = p - 1;

    f32x4 acc0[2], acc1[2];  // [mfrag] for this wave's (gate wg, n16 wn)
    if (do0) {
#pragma unroll
      for (int mf = 0; mf < 2; mf++)
#pragma unroll
        for (int i = 0; i < 4; i++) {
          int row = mb * 32 + mf * 16 + q * 4 + i;
          int tk = tok[row * TT + t0];
          int col = ct2 * 32 + wn * 16 + c15 + wg * 512;
          acc0[mf][i] = Pstate[(size_t)row * NG + col] + Pvocab[(size_t)tk * NG + col];
        }
    }
    if (do1) {
      float bv = b1[ct2 * 32 + wn * 16 + c15 + wg * 512];
#pragma unroll
      for (int mf = 0; mf < 2; mf++)
#pragma unroll
        for (int i = 0; i < 4; i++) acc1[mf][i] = bv;
    }

    auto aload = [&](int kc) -> unsigned long long {
      const unsigned short* hb = (kc < 16) ? h0r : h1r;
      return ald64(hb + (hchunk + (kc & 15)) * 4096 + a_src);
    };
    auto dswr = [&](int sb, unsigned long long v) {
      *(unsigned long long*)&ldsA[sb][a_lds] = v;
    };
    auto mmac = [&](int sb, bool on0, bf16x8 B0h, bf16x8 B0l, bf16x8 B1h, bf16x8 B1l) {
      bf16x8 ahi0 = *(const bf16x8*)&ldsA[sb][lane * 8];
      bf16x8 ahi1 = *(const bf16x8*)&ldsA[sb][512 + lane * 8];
      bf16x8 alo0 = *(const bf16x8*)&ldsA[sb][1024 + lane * 8];
      bf16x8 alo1 = *(const bf16x8*)&ldsA[sb][1536 + lane * 8];
      if (on0) {
        acc0[0] = __builtin_amdgcn_mfma_f32_16x16x32_bf16(ahi0, B0h, acc0[0], 0, 0, 0);
        acc0[0] = __builtin_amdgcn_mfma_f32_16x16x32_bf16(ahi0, B0l, acc0[0], 0, 0, 0);
        acc0[0] = __builtin_amdgcn_mfma_f32_16x16x32_bf16(alo0, B0h, acc0[0], 0, 0, 0);
        acc0[1] = __builtin_amdgcn_mfma_f32_16x16x32_bf16(ahi1, B0h, acc0[1], 0, 0, 0);
        acc0[1] = __builtin_amdgcn_mfma_f32_16x16x32_bf16(ahi1, B0l, acc0[1], 0, 0, 0);
        acc0[1] = __builtin_amdgcn_mfma_f32_16x16x32_bf16(alo1, B0h, acc0[1], 0, 0, 0);
      }
      if (do1) {
        acc1[0] = __builtin_amdgcn_mfma_f32_16x16x32_bf16(ahi0, B1h, acc1[0], 0, 0, 0);
        acc1[0] = __builtin_amdgcn_mfma_f32_16x16x32_bf16(ahi0, B1l, acc1[0], 0, 0, 0);
        acc1[0] = __builtin_amdgcn_mfma_f32_16x16x32_bf16(alo0, B1h, acc1[0], 0, 0, 0);
        acc1[1] = __builtin_amdgcn_mfma_f32_16x16x32_bf16(ahi1, B1h, acc1[1], 0, 0, 0);
        acc1[1] = __builtin_amdgcn_mfma_f32_16x16x32_bf16(ahi1, B1l, acc1[1], 0, 0, 0);
        acc1[1] = __builtin_amdgcn_mfma_f32_16x16x32_bf16(alo1, B1h, acc1[1], 0, 0, 0);
      }
    };

    const int R = do1 ? 32 : 16;

    // B register pipeline: Ba=B(kc), Bb=B(kc+1); Bc/Bd = incoming kc+2/kc+3
    bf16x8 Ba0h = {}, Ba0l = {}, Ba1h = {}, Ba1l = {};
    bf16x8 Bb0h = {}, Bb0l = {}, Bb1h = {}, Bb1l = {};
    bf16x8 Bc0h = {}, Bc0l = {}, Bc1h = {}, Bc1l = {};
    bf16x8 Bd0h = {}, Bd0l = {}, Bd1h = {}, Bd1l = {};
    if (do0) {
      Ba0h = *(const bf16x8*)(w0base);
      Ba0l = *(const bf16x8*)(w0base + 2048);
      Bb0h = *(const bf16x8*)(w0base + 4096);
      Bb0l = *(const bf16x8*)(w0base + 4096 + 2048);
    }
    if (do1) {
      Ba1h = *(const bf16x8*)(w1base);
      Ba1l = *(const bf16x8*)(w1base + 2048);
      Bb1h = *(const bf16x8*)(w1base + 4096);
      Bb1l = *(const bf16x8*)(w1base + 4096 + 2048);
    }
    unsigned long long a0v = aload(0);
    unsigned long long aN1 = aload(1);
    unsigned long long aN2 = aload(2);
    unsigned long long aN3 = aload(3);
    unsigned long long aN4 = aload(4);
    dswr(0, a0v);
    ldsbar();

#pragma unroll 1
    for (int kc = 0; kc < R; kc += 2) {
      unsigned long long aF0 = aload(kc + 5);
      unsigned long long aF1 = aload(kc + 6);
      if (do0 && kc + 2 < 16) {
        const unsigned short* s = w0base + (size_t)(kc + 2) * 4096;
        Bc0h = *(const bf16x8*)(s);
        Bc0l = *(const bf16x8*)(s + 2048);
      }
      if (do1 && kc + 2 < R) {
        const unsigned short* s = w1base + (size_t)(kc + 2) * 4096;
        Bc1h = *(const bf16x8*)(s);
        Bc1l = *(const bf16x8*)(s + 2048);
      }
      if (do0 && kc + 3 < 16) {
        const unsigned short* s = w0base + (size_t)(kc + 3) * 4096;
        Bd0h = *(const bf16x8*)(s);
        Bd0l = *(const bf16x8*)(s + 2048);
      }
      if (do1 && kc + 3 < R) {
        const unsigned short* s = w1base + (size_t)(kc + 3) * 4096;
        Bd1h = *(const bf16x8*)(s);
        Bd1l = *(const bf16x8*)(s + 2048);
      }
      dswr(1, aN1);
      mmac(0, do0 && kc < 16, Ba0h, Ba0l, Ba1h, Ba1l);
      ldsbar();
      dswr(0, aN2);
      mmac(1, do0 && kc + 1 < 16, Bb0h, Bb0l, Bb1h, Bb1l);
      ldsbar();
      aN1 = aN3; aN2 = aN4; aN3 = aF0; aN4 = aF1;
      Ba0h = Bc0h; Ba0l = Bc0l; Ba1h = Bc1h; Ba1l = Bc1l;
      Bb0h = Bd0h; Bb0l = Bd0l; Bb1h = Bd1h; Bb1l = Bd1l;
    }

    // ---- merged epilogue ----
    if (do0) {
#pragma unroll
      for (int mf = 0; mf < 2; mf++)
#pragma unroll
        for (int i = 0; i < 4; i++)
          xch[0][mf * 16 + q * 4 + i][wg * 32 + wn * 16 + c15] = acc0[mf][i];
    }
    if (do1) {
#pragma unroll
      for (int mf = 0; mf < 2; mf++)
#pragma unroll
        for (int i = 0; i < 4; i++)
          xch[1][mf * 16 + q * 4 + i][wg * 32 + wn * 16 + c15] = acc1[mf][i];
    }
    __syncthreads();
    {
      int rr = tid >> 4, cc = (tid & 15) * 2;
      int row = mb * 32 + rr;
      int cell = ct2 * 32 + cc;
      int qp = cc >> 3, jp = cc & 7;
      size_t hb = (hchunk + ct2) * 4096 + (size_t)(mfbase + (rr >> 4)) * 512 +
                  (size_t)((rr & 15) | (qp << 4)) * 8 + jp;
      int len = lens[row];
      if (do0) {
        bool msk = t0 < len;
        unsigned hhp, hlp;
        if (msk) {
          float gi0 = xch[0][rr][cc], gj0 = xch[0][rr][32 + cc];
          float gf0 = xch[0][rr][64 + cc], go0 = xch[0][rr][96 + cc];
          float gi1 = xch[0][rr][cc + 1], gj1 = xch[0][rr][33 + cc];
          float gf1 = xch[0][rr][65 + cc], go1 = xch[0][rr][97 + cc];
          size_t sidx = (size_t)row * HH + cell;
          float nca = c0[sidx] * sigm(gf0 + 1.f) + sigm(gi0) * tanhf(gj0);
          float ncb = c0[sidx + 1] * sigm(gf1 + 1.f) + sigm(gi1) * tanhf(gj1);
          float nha = tanhf(nca) * sigm(go0);
          float nhb = tanhf(ncb) * sigm(go1);
          c0[sidx] = nca; c0[sidx + 1] = ncb;
          unsigned short ha = f2bf(nha), hbq = f2bf(nhb);
          unsigned short la = f2bf(nha - bf2f(ha)), lb = f2bf(nhb - bf2f(hbq));
          hhp = ha | ((unsigned)hbq << 16);
          hlp = la | ((unsigned)lb << 16);
        } else {
          hhp = ald32(h0r + hb);
          hlp = ald32(h0r + hb + 2048);
        }
        ast32(h0w + hb, hhp);
        ast32(h0w + hb + 2048, hlp);
      }
      if (do1) {
        bool msk = t1 < len;
        unsigned hhp, hlp;
        if (msk) {
          float gi0 = xch[1][rr][cc], gj0 = xch[1][rr][32 + cc];
          float gf0 = xch[1][rr][64 + cc], go0 = xch[1][rr][96 + cc];
          float gi1 = xch[1][rr][cc + 1], gj1 = xch[1][rr][33 + cc];
          float gf1 = xch[1][rr][65 + cc], go1 = xch[1][rr][97 + cc];
          size_t sidx = (size_t)row * HH + cell;
          float nca = c1[sidx] * sigm(gf0 + 1.f) + sigm(gi0) * tanhf(gj0);
          float ncb = c1[sidx + 1] * sigm(gf1 + 1.f) + sigm(gi1) * tanhf(gj1);
          float nha = tanhf(nca) * sigm(go0);
          float nhb = tanhf(ncb) * sigm(go1);
          c1[sidx] = nca; c1[sidx + 1] = ncb;
          unsigned short ha = f2bf(nha), hbq = f2bf(nhb);
          unsigned short la = f2bf(nha - bf2f(ha)), lb = f2bf(nhb - bf2f(hbq));
          hhp = ha | ((unsigned)hbq << 16);
          hlp = la | ((unsigned)lb << 16);
        } else {
          hhp = ald32(h1r + hb);
          hlp = ald32(h1r + hb + 2048);
        }
        ast32(h1w + hb, hhp);
        ast32(h1w + hb + 2048, hlp);
        unsigned op = msk ? hhp : 0u;
        size_t oidx = ((size_t)row * 2 + (t1 >> 6)) * 32768 + (size_t)ct2 * 2048 +
                      (size_t)((t1 >> 4) & 3) * 512 +
                      (size_t)((t1 & 15) | (qp << 4)) * 8 + jp;
        __builtin_nontemporal_store(op, (unsigned*)&outsF[oidx]);
      }
    }

    if (p == TT) break;
    // per-mb group barrier: only the 16 blocks sharing these rows
    groupbar(gctr, 16u * (unsigned)(p + 1));
  }
}

// -------- projection via MFMA --------
__global__ __launch_bounds__(128) void proj_kernel(
    const unsigned short* __restrict__ outsF, const unsigned short* __restrict__ Wpf,
    const float* __restrict__ bp, float* __restrict__ out) {
  const int btile = blockIdx.x;
  const int tid = threadIdx.x;
  const int wN = tid >> 6;
  const int lane = tid & 63;
  const int c15 = lane & 15, q = lane >> 4;

  __shared__ __align__(16) unsigned short ldsA[2 * 2048];
  __shared__ __align__(16) unsigned short ldsB2[2 * 8192];

  f32x4 acc[4][4];
#pragma unroll
  for (int m = 0; m < 4; m++)
#pragma unroll
    for (int g = 0; g < 4; g++)
#pragma unroll
      for (int i = 0; i < 4; i++) acc[m][g][i] = 0.f;

  const unsigned short* asrcb = outsF + (size_t)btile * 32768;

  auto stageK = [&](int kc, int buf) {
#pragma unroll
    for (int i2 = 0; i2 < 8; i2++) {
      int f = wN * 8 + i2;
      gl16(&ldsB2[buf * 8192 + f * 512 + lane * 8],
           Wpf + (size_t)kc * 8192 + f * 512 + lane * 8);
    }
#pragma unroll
    for (int i2 = 0; i2 < 2; i2++) {
      int f = wN * 2 + i2;
      gl16(&ldsA[buf * 2048 + f * 512 + lane * 8],
           asrcb + (size_t)kc * 2048 + f * 512 + lane * 8);
    }
  };

  stageK(0, 0);
  __syncthreads();
  for (int kc = 0; kc < 16; kc++) {
    const int buf = kc & 1;
    if (kc + 1 < 16) stageK(kc + 1, buf ^ 1);
    bf16x8 a[4];
#pragma unroll
    for (int m = 0; m < 4; m++)
      a[m] = *(const bf16x8*)&ldsA[buf * 2048 + m * 512 + lane * 8];
#pragma unroll
    for (int g = 0; g < 4; g++) {
      int ni = wN * 4 + g;
      bf16x8 bhi = *(const bf16x8*)&ldsB2[buf * 8192 + ni * 512 + lane * 8];
      bf16x8 blo = *(const bf16x8*)&ldsB2[buf * 8192 + 4096 + ni * 512 + lane * 8];
#pragma unroll
      for (int m = 0; m < 4; m++) {
        acc[m][g] = __builtin_amdgcn_mfma_f32_16x16x32_bf16(a[m], bhi, acc[m][g], 0, 0, 0);
        acc[m][g] = __builtin_amdgcn_mfma_f32_16x16x32_bf16(a[m], blo, acc[m][g], 0, 0, 0);
      }
    }
    __syncthreads();
  }

#pragma unroll
  for (int g = 0; g < 4; g++) {
    int col = (wN * 4 + g) * 16 + c15;
    if (col < VV) {
      float bpv = bp[col];
#pragma unroll
      for (int m = 0; m < 4; m++)
#pragma unroll
        for (int i = 0; i < 4; i++) {
          int rowBT = btile * 64 + m * 16 + q * 4 + i;
          out[(size_t)rowBT * VV + col] = acc[m][g][i] + bpv;
        }
    }
  }
}

extern "C" void kernel_launch(void* const* d_in, const int* in_sizes, int n_in,
                              void* d_out, int out_size, void* d_ws, size_t ws_size,
                              hipStream_t stream) {
  const int* tok = (const int*)d_in[0];
  const int* lens = (const int*)d_in[1];
  const float* state = (const float*)d_in[2];
  const float* cemb = (const float*)d_in[3];
  const float* W0 = (const float*)d_in[4];
  const float* b0 = (const float*)d_in[5];
  const float* W1 = (const float*)d_in[6];
  const float* b1 = (const float*)d_in[7];
  const float* Wp = (const float*)d_in[8];
  const float* bp = (const float*)d_in[9];
  float* out = (float*)d_out;

  char* wsp = (char*)d_ws;
  float* Pstate = (float*)wsp; wsp += (size_t)BB * NG * 4;                        // 4 MB
  float* Pvocab = (float*)wsp; wsp += (size_t)VV * NG * 4;                        // 800 KB
  unsigned short* W0f = (unsigned short*)wsp; wsp += (size_t)32 * 16 * 4096 * 2;  // 4 MB
  unsigned short* W1f = (unsigned short*)wsp; wsp += (size_t)32 * 32 * 4096 * 2;  // 8 MB
  unsigned short* Wpf = (unsigned short*)wsp; wsp += (size_t)16 * 8192 * 2;       // 256 KB
  unsigned short* h0f = (unsigned short*)wsp; wsp += (size_t)2 * 524288 * 2;      // 2 MB
  unsigned short* h1f = (unsigned short*)wsp; wsp += (size_t)2 * 524288 * 2;      // 2 MB
  float* c0 = (float*)wsp; wsp += (size_t)BB * HH * 4;                            // 1 MB
  float* c1 = (float*)wsp; wsp += (size_t)BB * HH * 4;                            // 1 MB
  unsigned int* bar = (unsigned int*)wsp; wsp += 8192;  // [0]=init, 64+64*mb=group
  int* slots = (int*)wsp; wsp += 1024;
  unsigned short* outsF = (unsigned short*)wsp;                                   // 64 MB

  // zero h0f,h1f,c0,c1,bar,slots (contiguous)
  hipMemsetAsync(h0f, 0, (size_t)6 * 1048576 + 8192 + 1024, stream);

  pv_kernel<<<(VV * NG + 255) / 256, 256, 0, stream>>>(cemb, W0, Pvocab);
  ps_kernel<<<256, 256, 0, stream>>>(state, W0, b0, Pstate);
  wconv_kernel<<<4096, 256, 0, stream>>>(W0, EE + HH, W0f, 15, 15);
  wconv_kernel<<<8192, 256, 0, stream>>>(W1, 0, W1f, 31, 16);
  wconvp_kernel<<<(16 * 4096) / 256, 256, 0, stream>>>(Wp, Wpf);

  fused_kernel<<<NBLK, 512, 0, stream>>>(tok, lens, Pstate, Pvocab, W0f, W1f, b1,
                                         h0f, h1f, c0, c1, outsF, bar, slots);

  proj_kernel<<<BB * TT / 64, 128, 0, stream>>>(outsF, Wpf, bp, out);
}